// Round 1
// baseline (434.428 us; speedup 1.0000x reference)
//
#include <hip/hip_runtime.h>

#define HW (512*512)
#define WMASK 511

// ---------------- Kernel A: percep -> MLP -> y; write normals + Aff + SA ----
__global__ __launch_bounds__(256) void nca_mlp(
    const float* __restrict__ x,
    const float* __restrict__ rmask,
    const float* __restrict__ w1w,   // (128, 64)
    const float* __restrict__ w1b,   // (128,)
    const float* __restrict__ w2w,   // (16, 128)
    float* __restrict__ out,         // (4,16,512,512) final; ch 0..2 get Aff (temp)
    float* __restrict__ SA)          // (4,512,512) sum of Aff
{
    int idx = blockIdx.x * 256 + threadIdx.x;   // < 4*HW
    int w = idx & WMASK;
    int h = (idx >> 9) & WMASK;
    int b = idx >> 18;
    int p = (h << 9) | w;

    const float* xb = x + b * 16 * HW;
    int hm = (h - 1) & WMASK, hp = (h + 1) & WMASK;
    int wm = (w - 1) & WMASK, wp = (w + 1) & WMASK;
    int r0 = hm << 9, r1 = h << 9, r2 = hp << 9;

    float percep[64];
#pragma unroll
    for (int c = 0; c < 16; ++c) {
        const float* xc = xb + c * HW;
        float a00 = xc[r0 + wm], a01 = xc[r0 + w], a02 = xc[r0 + wp];
        float a10 = xc[r1 + wm], a11 = xc[r1 + w], a12 = xc[r1 + wp];
        float a20 = xc[r2 + wm], a21 = xc[r2 + w], a22 = xc[r2 + wp];
        percep[c] = a11;
        // SOBEL_X (cross-correlation, rows = h-offset, cols = w-offset)
        percep[16 + c*3 + 0] = (a02 - a00) + 2.f*(a12 - a10) + (a22 - a20);
        // SOBEL_X^T
        percep[16 + c*3 + 1] = (a20 - a00) + 2.f*(a21 - a01) + (a22 - a02);
        // LAP
        percep[16 + c*3 + 2] = a00 + 2.f*a01 + a02
                             + 2.f*a10 - 12.f*a11 + 2.f*a12
                             + a20 + 2.f*a21 + a22;
    }

    float y[16];
#pragma unroll
    for (int c = 0; c < 16; ++c) y[c] = 0.f;

    for (int k = 0; k < 128; ++k) {
        float hk = w1b[k];
        const float* wk = w1w + k * 64;     // wave-uniform -> s_load
#pragma unroll
        for (int c = 0; c < 64; ++c) hk = fmaf(wk[c], percep[c], hk);
        hk = fmaxf(hk, 0.f);
#pragma unroll
        for (int c = 0; c < 16; ++c) y[c] = fmaf(w2w[c*128 + k], hk, y[c]);
    }

    float mask = floorf(rmask[b*HW + p] + 0.5f);
#pragma unroll
    for (int c = 3; c < 16; ++c)
        out[(b*16 + c)*HW + p] = xb[c*HW + p] + y[c] * mask;

    float A0 = expf(0.1f * y[0]);
    float A1 = expf(0.1f * y[1]);
    float A2 = expf(0.1f * y[2]);
    out[(b*16 + 0)*HW + p] = A0;
    out[(b*16 + 1)*HW + p] = A1;
    out[(b*16 + 2)*HW + p] = A2;
    SA[b*HW + p] = A0 + A1 + A2;
}

// ---------------- Kernel B: T = Smass / E,  E = 3x3 wrap-sum of SA ---------
__global__ __launch_bounds__(256) void nca_T(
    const float* __restrict__ x,
    const float* __restrict__ SA,
    float* __restrict__ T)
{
    int idx = blockIdx.x * 256 + threadIdx.x;
    int w = idx & WMASK;
    int h = (idx >> 9) & WMASK;
    int b = idx >> 18;
    int p = (h << 9) | w;

    const float* sab = SA + b * HW;
    int hm = (h - 1) & WMASK, hp = (h + 1) & WMASK;
    int wm = (w - 1) & WMASK, wp = (w + 1) & WMASK;
    int r0 = hm << 9, r1 = h << 9, r2 = hp << 9;

    float E = sab[r0+wm] + sab[r0+w] + sab[r0+wp]
            + sab[r1+wm] + sab[r1+w] + sab[r1+wp]
            + sab[r2+wm] + sab[r2+w] + sab[r2+wp];

    const float* xb = x + b * 16 * HW;
    float Smass = xb[p] + xb[HW + p] + xb[2*HW + p];
    T[b*HW + p] = Smass / E;
}

// ---------------- Kernel C: out[0..2] = Aff * (3x3 wrap-sum of T) ----------
__global__ __launch_bounds__(256) void nca_mass(
    const float* __restrict__ T,
    float* __restrict__ out)
{
    int idx = blockIdx.x * 256 + threadIdx.x;
    int w = idx & WMASK;
    int h = (idx >> 9) & WMASK;
    int b = idx >> 18;
    int p = (h << 9) | w;

    const float* tb = T + b * HW;
    int hm = (h - 1) & WMASK, hp = (h + 1) & WMASK;
    int wm = (w - 1) & WMASK, wp = (w + 1) & WMASK;
    int r0 = hm << 9, r1 = h << 9, r2 = hp << 9;

    float R = tb[r0+wm] + tb[r0+w] + tb[r0+wp]
            + tb[r1+wm] + tb[r1+w] + tb[r1+wp]
            + tb[r2+wm] + tb[r2+w] + tb[r2+wp];

#pragma unroll
    for (int c = 0; c < 3; ++c) {
        int o = (b*16 + c)*HW + p;
        out[o] = out[o] * R;    // own-pixel read-then-write: no race
    }
}

extern "C" void kernel_launch(void* const* d_in, const int* in_sizes, int n_in,
                              void* d_out, int out_size, void* d_ws, size_t ws_size,
                              hipStream_t stream) {
    const float* x     = (const float*)d_in[0];
    const float* rmask = (const float*)d_in[1];
    const float* w1w   = (const float*)d_in[2];
    const float* w1b   = (const float*)d_in[3];
    const float* w2w   = (const float*)d_in[4];
    float* out = (float*)d_out;

    float* SA = (float*)d_ws;          // 4*HW floats = 4 MiB
    float* T  = SA + 4*HW;             // 4*HW floats = 4 MiB

    int total = 4 * HW;                // 1,048,576 pixels
    dim3 block(256), grid(total / 256);

    hipLaunchKernelGGL(nca_mlp,  grid, block, 0, stream, x, rmask, w1w, w1b, w2w, out, SA);
    hipLaunchKernelGGL(nca_T,    grid, block, 0, stream, x, SA, T);
    hipLaunchKernelGGL(nca_mass, grid, block, 0, stream, T, out);
}

// Round 2
// 270.134 us; speedup vs baseline: 1.6082x; 1.6082x over previous
//
#include <hip/hip_runtime.h>

#define HW (512*512)
#define WMASK 511

typedef short bf16x8 __attribute__((ext_vector_type(8)));
typedef float f32x4 __attribute__((ext_vector_type(4)));

__device__ __forceinline__ unsigned short f2bf(float f) {
    union { float f; unsigned int u; } v; v.f = f;
    unsigned int r = (v.u + 0x7FFFu + ((v.u >> 16) & 1u)) >> 16;   // RNE
    return (unsigned short)r;
}

// percep K-permutation: c_new = s8*8 + b*4 + f  -> channel ch = 2*s8+b, feature f
// f: 0=center, 1=sobel_x, 2=sobel_y, 3=lap.  original index: f==0 ? ch : 16+ch*3+(f-1)
__device__ __forceinline__ int corig(int c) {
    int s8 = c >> 3, b = (c >> 2) & 1, f = c & 3;
    int ch = 2*s8 + b;
    return (f == 0) ? ch : (16 + ch*3 + (f - 1));
}

// ---------------- Kernel A: percep -> bf16 MFMA MLP -> normals + Aff + SA ---
__global__ __launch_bounds__(256) void nca_mlp_mfma(
    const float* __restrict__ x,
    const float* __restrict__ rmask,
    const float* __restrict__ w1w,   // (128, 64) fp32
    const float* __restrict__ w1b,   // (128,)
    const float* __restrict__ w2w,   // (16, 128)
    float* __restrict__ out,         // (4,16,512,512); ch0..2 get Aff (temp)
    float* __restrict__ SA)          // (4,512,512)
{
    // LDS: w1 fragments [m2=(m*2+ks)][lane][8], w2 fragments [s][lane][8], bias
    __shared__ __align__(16) unsigned short w1s[16*64*8];  // 16 KB
    __shared__ __align__(16) unsigned short w2s[4*64*8];   // 4 KB
    __shared__ float w1bs[128];

    int tid  = threadIdx.x;
    int lane = tid & 63;
    int wv   = tid >> 6;
    int q    = lane >> 4;      // 0..3 (k-slice group)
    int r    = lane & 15;      // pixel-within-tile / row-within-tile

    // ---- stage weights as MFMA fragments (bf16, packed pairs) ----
    unsigned int* w1s32 = (unsigned int*)w1s;
    for (int u = tid; u < 4096; u += 256) {
        int m2 = u >> 8;             // (m*2+ks), m=m2>>1, ks=m2&1
        int ln = (u >> 2) & 63;
        int d  = u & 3;
        int m  = m2 >> 1, ks = m2 & 1;
        int qq = ln >> 4, row = ln & 15;
        int c0 = ks*32 + qq*8 + 2*d;
        int hr = m*16 + row;
        unsigned int lo = f2bf(w1w[hr*64 + corig(c0)]);
        unsigned int hi = f2bf(w1w[hr*64 + corig(c0+1)]);
        w1s32[u] = lo | (hi << 16);
    }
    unsigned int* w2s32 = (unsigned int*)w2s;
    for (int u = tid; u < 1024; u += 256) {
        int s  = u >> 8;
        int ln = (u >> 2) & 63;
        int d  = u & 3;
        int qq = ln >> 4, ych = ln & 15;
        int k0 = s*32 + qq*8 + 2*d;
        unsigned int lo = f2bf(w2w[ych*128 + k0]);
        unsigned int hi = f2bf(w2w[ych*128 + k0 + 1]);
        w2s32[u] = lo | (hi << 16);
    }
    if (tid < 128) w1bs[tid] = w1b[tid];

    // ---- geometry ----
    int bIdx = blockIdx.x >> 10;          // batch 0..3
    int blk  = blockIdx.x & 1023;
    int hrow = blk >> 1;                  // 0..511
    int wbase = ((blk & 1) << 8) + (wv << 6);

    int rm = ((hrow - 1) & WMASK) << 9;
    int rc = hrow << 9;
    int rp = ((hrow + 1) & WMASK) << 9;

    const float* xb = x + bIdx*16*HW;

    // ---- percep B-fragments: pf[P][ks], lane(q,r) covers channels {8ks+2q, 8ks+2q+1}
    bf16x8 pf[4][2];
#pragma unroll
    for (int P = 0; P < 4; ++P) {
        int col = wbase + P*16 + r;
        int cm = (col - 1) & WMASK, cp = (col + 1) & WMASK;
#pragma unroll
        for (int ks = 0; ks < 2; ++ks) {
#pragma unroll
            for (int b = 0; b < 2; ++b) {
                int ch = 8*ks + 2*q + b;
                const float* pl = xb + ch*HW;
                float a00=pl[rm+cm], a01=pl[rm+col], a02=pl[rm+cp];
                float a10=pl[rc+cm], a11=pl[rc+col], a12=pl[rc+cp];
                float a20=pl[rp+cm], a21=pl[rp+col], a22=pl[rp+cp];
                float sx = (a02-a00) + 2.f*(a12-a10) + (a22-a20);
                float sy = (a20-a00) + 2.f*(a21-a01) + (a22-a02);
                float lp = a00 + 2.f*a01 + a02 + 2.f*a10 - 12.f*a11 + 2.f*a12
                         + a20 + 2.f*a21 + a22;
                pf[P][ks][b*4+0] = (short)f2bf(a11);
                pf[P][ks][b*4+1] = (short)f2bf(sx);
                pf[P][ks][b*4+2] = (short)f2bf(sy);
                pf[P][ks][b*4+3] = (short)f2bf(lp);
            }
        }
    }

    __syncthreads();

    // ---- MLP: layer1 (h^T = w1 @ percep^T), transpose, layer2 (y = w2 @ h) ----
    f32x4 yacc[4];
#pragma unroll
    for (int P = 0; P < 4; ++P) { yacc[P][0]=0.f; yacc[P][1]=0.f; yacc[P][2]=0.f; yacc[P][3]=0.f; }

#pragma unroll
    for (int s = 0; s < 4; ++s) {
        f32x4 Hc[2][4];
#pragma unroll
        for (int t = 0; t < 2; ++t)
#pragma unroll
            for (int P = 0; P < 4; ++P) { Hc[t][P][0]=0.f; Hc[t][P][1]=0.f; Hc[t][P][2]=0.f; Hc[t][P][3]=0.f; }

#pragma unroll
        for (int t = 0; t < 2; ++t) {
#pragma unroll
            for (int ks = 0; ks < 2; ++ks) {
                bf16x8 af = *(const bf16x8*)&w1s[(((2*s+t)*2 + ks)*64 + lane)*8];
#pragma unroll
                for (int P = 0; P < 4; ++P)
                    Hc[t][P] = __builtin_amdgcn_mfma_f32_16x16x32_bf16(af, pf[P][ks], Hc[t][P], 0, 0, 0);
            }
        }

        bf16x8 wf = *(const bf16x8*)&w2s[((s*64) + lane)*8];
        float bi0[2][4];
#pragma unroll
        for (int t = 0; t < 2; ++t) {
            const float* bp = &w1bs[(2*s+t)*16 + (q<<2)];
#pragma unroll
            for (int i = 0; i < 4; ++i) bi0[t][i] = bp[i];
        }

        int ga = ((q & 1) << 5) | r;   // source lane for elems 0..3
        int gb = ga + 16;              // source lane for elems 4..7
        bool hiT = (q >= 2);

#pragma unroll
        for (int P = 0; P < 4; ++P) {
            unsigned int pk00, pk01, pk10, pk11;
            {
                f32x4 hv = Hc[0][P];
                float h0 = fmaxf(hv[0] + bi0[0][0], 0.f);
                float h1 = fmaxf(hv[1] + bi0[0][1], 0.f);
                float h2 = fmaxf(hv[2] + bi0[0][2], 0.f);
                float h3 = fmaxf(hv[3] + bi0[0][3], 0.f);
                pk00 = (unsigned int)f2bf(h0) | ((unsigned int)f2bf(h1) << 16);
                pk01 = (unsigned int)f2bf(h2) | ((unsigned int)f2bf(h3) << 16);
            }
            {
                f32x4 hv = Hc[1][P];
                float h0 = fmaxf(hv[0] + bi0[1][0], 0.f);
                float h1 = fmaxf(hv[1] + bi0[1][1], 0.f);
                float h2 = fmaxf(hv[2] + bi0[1][2], 0.f);
                float h3 = fmaxf(hv[3] + bi0[1][3], 0.f);
                pk10 = (unsigned int)f2bf(h0) | ((unsigned int)f2bf(h1) << 16);
                pk11 = (unsigned int)f2bf(h2) | ((unsigned int)f2bf(h3) << 16);
            }
            // cross-lane transpose: C-layout h^T -> layer2 B-fragment
            unsigned int s00 = (unsigned int)__shfl((int)pk00, ga);
            unsigned int s10 = (unsigned int)__shfl((int)pk10, ga);
            unsigned int s01 = (unsigned int)__shfl((int)pk01, ga);
            unsigned int s11 = (unsigned int)__shfl((int)pk11, ga);
            unsigned int s02 = (unsigned int)__shfl((int)pk00, gb);
            unsigned int s12 = (unsigned int)__shfl((int)pk10, gb);
            unsigned int s03 = (unsigned int)__shfl((int)pk01, gb);
            unsigned int s13 = (unsigned int)__shfl((int)pk11, gb);
            union { unsigned int u[4]; bf16x8 v; } bb;
            bb.u[0] = hiT ? s10 : s00;
            bb.u[1] = hiT ? s11 : s01;
            bb.u[2] = hiT ? s12 : s02;
            bb.u[3] = hiT ? s13 : s03;
            yacc[P] = __builtin_amdgcn_mfma_f32_16x16x32_bf16(wf, bb.v, yacc[P], 0, 0, 0);
        }
    }

    // ---- epilogue: lane(q,r) holds y channels q*4+i for pixel P*16+r ----
#pragma unroll
    for (int P = 0; P < 4; ++P) {
        int col = wbase + P*16 + r;
        int p = rc | col;
        float msk = floorf(rmask[bIdx*HW + p] + 0.5f);
        f32x4 yv = yacc[P];
        if (q == 0) {
            float A0 = expf(0.1f * yv[0]);
            float A1 = expf(0.1f * yv[1]);
            float A2 = expf(0.1f * yv[2]);
            out[(bIdx*16 + 0)*HW + p] = A0;
            out[(bIdx*16 + 1)*HW + p] = A1;
            out[(bIdx*16 + 2)*HW + p] = A2;
            SA[bIdx*HW + p] = A0 + A1 + A2;
            out[(bIdx*16 + 3)*HW + p] = xb[3*HW + p] + yv[3] * msk;
        } else {
#pragma unroll
            for (int i = 0; i < 4; ++i) {
                int ch = q*4 + i;
                out[(bIdx*16 + ch)*HW + p] = xb[ch*HW + p] + yv[i] * msk;
            }
        }
    }
}

// ---------------- Kernel BC: fused  T = Smass/E  and  out[0..2] *= 3x3sum(T) -
__global__ __launch_bounds__(256) void nca_bc(
    const float* __restrict__ x,
    const float* __restrict__ SA,
    float* __restrict__ out)
{
    __shared__ float sa[36][37];
    __shared__ float tt[34][35];
    int tid = threadIdx.x;
    int bb   = blockIdx.x >> 8;
    int tile = blockIdx.x & 255;
    int h0 = (tile >> 4) << 5;
    int w0 = (tile & 15) << 5;
    const float* sab = SA + bb*HW;

    for (int e = tid; e < 1296; e += 256) {           // 36x36 SA halo
        int rr = e / 36, cc = e - rr*36;
        int gh = (h0 + rr - 2) & WMASK, gw = (w0 + cc - 2) & WMASK;
        sa[rr][cc] = sab[(gh<<9) | gw];
    }
    __syncthreads();

    const float* xb = x + bb*16*HW;
    for (int e = tid; e < 1156; e += 256) {           // 34x34 T
        int rr = e / 34, cc = e - rr*34;
        float E = sa[rr  ][cc] + sa[rr  ][cc+1] + sa[rr  ][cc+2]
                + sa[rr+1][cc] + sa[rr+1][cc+1] + sa[rr+1][cc+2]
                + sa[rr+2][cc] + sa[rr+2][cc+1] + sa[rr+2][cc+2];
        int gh = (h0 + rr - 1) & WMASK, gw = (w0 + cc - 1) & WMASK;
        int g = (gh<<9) | gw;
        float Sm = xb[g] + xb[HW + g] + xb[2*HW + g];
        tt[rr][cc] = Sm / E;
    }
    __syncthreads();

    for (int e = tid; e < 1024; e += 256) {           // 32x32 out
        int rr = e >> 5, cc = e & 31;
        float R = tt[rr  ][cc] + tt[rr  ][cc+1] + tt[rr  ][cc+2]
                + tt[rr+1][cc] + tt[rr+1][cc+1] + tt[rr+1][cc+2]
                + tt[rr+2][cc] + tt[rr+2][cc+1] + tt[rr+2][cc+2];
        int p = ((h0 + rr) << 9) | (w0 + cc);
        float* ob = out + bb*16*HW + p;
        ob[0]    *= R;
        ob[HW]   *= R;
        ob[2*HW] *= R;
    }
}

extern "C" void kernel_launch(void* const* d_in, const int* in_sizes, int n_in,
                              void* d_out, int out_size, void* d_ws, size_t ws_size,
                              hipStream_t stream) {
    const float* x     = (const float*)d_in[0];
    const float* rmask = (const float*)d_in[1];
    const float* w1w   = (const float*)d_in[2];
    const float* w1b   = (const float*)d_in[3];
    const float* w2w   = (const float*)d_in[4];
    float* out = (float*)d_out;
    float* SA  = (float*)d_ws;            // 4*HW floats

    hipLaunchKernelGGL(nca_mlp_mfma, dim3(4096), dim3(256), 0, stream,
                       x, rmask, w1w, w1b, w2w, out, SA);
    hipLaunchKernelGGL(nca_bc, dim3(1024), dim3(256), 0, stream, x, SA, out);
}

// Round 4
// 187.121 us; speedup vs baseline: 2.3216x; 1.4436x over previous
//
#include <hip/hip_runtime.h>

#define HW (512*512)
#define WMASK 511

typedef short bf16x8 __attribute__((ext_vector_type(8)));
typedef float f32x4 __attribute__((ext_vector_type(4)));
typedef unsigned int u32x4 __attribute__((ext_vector_type(4)));

__device__ __forceinline__ unsigned short f2bf(float f) {
    union { float f; unsigned int u; } v; v.f = f;
    unsigned int r = (v.u + 0x7FFFu + ((v.u >> 16) & 1u)) >> 16;   // RNE
    return (unsigned short)r;
}
// percep K-permutation: c_new = s8*8 + b*4 + f -> ch = 2*s8+b, feature f
__device__ __forceinline__ int corig(int c) {
    int s8 = c >> 3, b = (c >> 2) & 1, f = c & 3;
    int ch = 2*s8 + b;
    return (f == 0) ? ch : (16 + ch*3 + (f - 1));
}

// ---- prep: stage weights into MFMA-fragment layout in ws (1 block, once) ---
__global__ __launch_bounds__(256) void nca_prep(
    const float* __restrict__ w1w, const float* __restrict__ w1b,
    const float* __restrict__ w2w, unsigned int* __restrict__ wbuf)
{
    int tid = threadIdx.x;
    for (int u = tid; u < 4096; u += 256) {          // w1 fragments
        int m2 = u >> 8, ln = (u >> 2) & 63, d = u & 3;
        int m = m2 >> 1, ks = m2 & 1;
        int qq = ln >> 4, row = ln & 15;
        int c0 = ks*32 + qq*8 + 2*d;
        int hr = m*16 + row;
        unsigned int lo = f2bf(w1w[hr*64 + corig(c0)]);
        unsigned int hi = f2bf(w1w[hr*64 + corig(c0+1)]);
        wbuf[u] = lo | (hi << 16);
    }
    for (int u = tid; u < 1024; u += 256) {          // w2 fragments
        int s = u >> 8, ln = (u >> 2) & 63, d = u & 3;
        int qq = ln >> 4, ych = ln & 15;
        int k0 = s*32 + qq*8 + 2*d;
        unsigned int lo = f2bf(w2w[ych*128 + k0]);
        unsigned int hi = f2bf(w2w[ych*128 + k0 + 1]);
        wbuf[4096 + u] = lo | (hi << 16);
    }
    if (tid < 128) {                                 // bias (fp32 bits)
        union { float f; unsigned int u; } v; v.f = w1b[tid];
        wbuf[5120 + tid] = v.u;
    }
}

// ---- Kernel A: percep (float4 loads, round-2-exact math) -> MFMA MLP -------
__global__ __launch_bounds__(256) void nca_mlp_mfma(
    const float* __restrict__ x,
    const float* __restrict__ rmask,
    const unsigned int* __restrict__ wbuf,
    float* __restrict__ out,
    float* __restrict__ SA)
{
    __shared__ __align__(16) unsigned int wsh[5248];   // 21 KB: w1|w2|bias
    int tid  = threadIdx.x;
    int lane = tid & 63;
    int wv   = tid >> 6;
    int q    = lane >> 4;
    int r    = lane & 15;

    // coalesced LDS fill of pre-staged weights
    {
        const u32x4* src = (const u32x4*)wbuf;
        u32x4* dst = (u32x4*)wsh;
#pragma unroll
        for (int u = 0; u < 6; ++u) {
            int idx = tid + u*256;
            if (idx < 1312) dst[idx] = src[idx];
        }
    }

    // geometry: block = 4 rows x 64 cols; wave wv owns one row; lane r owns
    // pixels (cols) c4..c4+3  (fragment P column r <-> pixel w0+4r+P)
    int bIdx = blockIdx.x >> 10;
    int rem  = blockIdx.x & 1023;
    int hrow = ((rem >> 3) << 2) + wv;
    int w0   = (rem & 7) << 6;
    int c4   = w0 + (r << 2);
    int cl   = (c4 - 1) & WMASK;
    int cr   = (c4 + 4) & WMASK;
    int rm = ((hrow-1)&WMASK)<<9, rc = hrow<<9, rp = ((hrow+1)&WMASK)<<9;
    const float* xb = x + bIdx*16*HW;

    // percep fragments: direct 9-point stencil, round-2-identical expressions
    union PFU { unsigned short s[8]; bf16x8 v; } pf[4][2];
#pragma unroll
    for (int ks = 0; ks < 2; ++ks) {
#pragma unroll
        for (int b2 = 0; b2 < 2; ++b2) {
            const float* pl = xb + (8*ks + 2*q + b2)*HW;
            f32x4 m0 = *(const f32x4*)(pl + rm + c4);
            f32x4 m1 = *(const f32x4*)(pl + rc + c4);
            f32x4 m2 = *(const f32x4*)(pl + rp + c4);
            float col[6][3];
            col[0][0] = pl[rm+cl]; col[0][1] = pl[rc+cl]; col[0][2] = pl[rp+cl];
#pragma unroll
            for (int j = 0; j < 4; ++j) {
                col[j+1][0] = m0[j]; col[j+1][1] = m1[j]; col[j+1][2] = m2[j];
            }
            col[5][0] = pl[rm+cr]; col[5][1] = pl[rc+cr]; col[5][2] = pl[rp+cr];
#pragma unroll
            for (int p = 0; p < 4; ++p) {
                float a00 = col[p][0],   a01 = col[p+1][0], a02 = col[p+2][0];
                float a10 = col[p][1],   a11 = col[p+1][1], a12 = col[p+2][1];
                float a20 = col[p][2],   a21 = col[p+1][2], a22 = col[p+2][2];
                float sx = (a02 - a00) + 2.f*(a12 - a10) + (a22 - a20);
                float sy = (a20 - a00) + 2.f*(a21 - a01) + (a22 - a02);
                float lp = a00 + 2.f*a01 + a02
                         + 2.f*a10 - 12.f*a11 + 2.f*a12
                         + a20 + 2.f*a21 + a22;
                pf[p][ks].s[b2*4+0] = (unsigned short)f2bf(a11);
                pf[p][ks].s[b2*4+1] = (unsigned short)f2bf(sx);
                pf[p][ks].s[b2*4+2] = (unsigned short)f2bf(sy);
                pf[p][ks].s[b2*4+3] = (unsigned short)f2bf(lp);
            }
        }
    }

    __syncthreads();

    const unsigned short* w1s = (const unsigned short*)wsh;
    const unsigned short* w2s = (const unsigned short*)(wsh + 4096);
    const float* w1bs = (const float*)(wsh + 5120);

    f32x4 yacc[4];
#pragma unroll
    for (int P = 0; P < 4; ++P) { yacc[P][0]=0.f; yacc[P][1]=0.f; yacc[P][2]=0.f; yacc[P][3]=0.f; }

#pragma unroll
    for (int s = 0; s < 4; ++s) {
        f32x4 Hc[2][4];
#pragma unroll
        for (int t = 0; t < 2; ++t)
#pragma unroll
            for (int P = 0; P < 4; ++P) { Hc[t][P][0]=0.f; Hc[t][P][1]=0.f; Hc[t][P][2]=0.f; Hc[t][P][3]=0.f; }

#pragma unroll
        for (int t = 0; t < 2; ++t) {
#pragma unroll
            for (int ks = 0; ks < 2; ++ks) {
                bf16x8 af = *(const bf16x8*)&w1s[(((2*s+t)*2 + ks)*64 + lane)*8];
#pragma unroll
                for (int P = 0; P < 4; ++P)
                    Hc[t][P] = __builtin_amdgcn_mfma_f32_16x16x32_bf16(af, pf[P][ks].v, Hc[t][P], 0, 0, 0);
            }
        }

        bf16x8 wf = *(const bf16x8*)&w2s[(s*64 + lane)*8];
        float bi0[2][4];
#pragma unroll
        for (int t = 0; t < 2; ++t) {
            const float* bp = &w1bs[(2*s+t)*16 + (q<<2)];
#pragma unroll
            for (int i = 0; i < 4; ++i) bi0[t][i] = bp[i];
        }

        int ga = ((q & 1) << 5) | r;
        int gb = ga + 16;
        bool hiT = (q >= 2);

#pragma unroll
        for (int P = 0; P < 4; ++P) {
            unsigned int pk00, pk01, pk10, pk11;
            {
                f32x4 hv = Hc[0][P];
                float h0 = fmaxf(hv[0] + bi0[0][0], 0.f);
                float h1 = fmaxf(hv[1] + bi0[0][1], 0.f);
                float h2 = fmaxf(hv[2] + bi0[0][2], 0.f);
                float h3 = fmaxf(hv[3] + bi0[0][3], 0.f);
                pk00 = (unsigned int)f2bf(h0) | ((unsigned int)f2bf(h1) << 16);
                pk01 = (unsigned int)f2bf(h2) | ((unsigned int)f2bf(h3) << 16);
            }
            {
                f32x4 hv = Hc[1][P];
                float h0 = fmaxf(hv[0] + bi0[1][0], 0.f);
                float h1 = fmaxf(hv[1] + bi0[1][1], 0.f);
                float h2 = fmaxf(hv[2] + bi0[1][2], 0.f);
                float h3 = fmaxf(hv[3] + bi0[1][3], 0.f);
                pk10 = (unsigned int)f2bf(h0) | ((unsigned int)f2bf(h1) << 16);
                pk11 = (unsigned int)f2bf(h2) | ((unsigned int)f2bf(h3) << 16);
            }
            unsigned int s00 = (unsigned int)__shfl((int)pk00, ga);
            unsigned int s10 = (unsigned int)__shfl((int)pk10, ga);
            unsigned int s01 = (unsigned int)__shfl((int)pk01, ga);
            unsigned int s11 = (unsigned int)__shfl((int)pk11, ga);
            unsigned int s02 = (unsigned int)__shfl((int)pk00, gb);
            unsigned int s12 = (unsigned int)__shfl((int)pk10, gb);
            unsigned int s03 = (unsigned int)__shfl((int)pk01, gb);
            unsigned int s13 = (unsigned int)__shfl((int)pk11, gb);
            union { unsigned int u[4]; bf16x8 v; } bb;
            bb.u[0] = hiT ? s10 : s00;
            bb.u[1] = hiT ? s11 : s01;
            bb.u[2] = hiT ? s12 : s02;
            bb.u[3] = hiT ? s13 : s03;
            yacc[P] = __builtin_amdgcn_mfma_f32_16x16x32_bf16(wf, bb.v, yacc[P], 0, 0, 0);
        }
    }

    // epilogue: yacc[P][i] = y[ch=4q+i][pixel c4+P]; all IO as float4
    int pbase = rc + c4;
    f32x4 mk = *(const f32x4*)(rmask + bIdx*HW + pbase);
#pragma unroll
    for (int i = 0; i < 4; ++i) mk[i] = floorf(mk[i] + 0.5f);
    float* ob = out + bIdx*16*HW;

    if (q == 0) {
        f32x4 sacc;
#pragma unroll
        for (int i = 0; i < 3; ++i) {
            f32x4 A;
#pragma unroll
            for (int P = 0; P < 4; ++P) A[P] = expf(0.1f * yacc[P][i]);
            *(f32x4*)(ob + i*HW + pbase) = A;
            if (i == 0) sacc = A; else sacc += A;
        }
        *(f32x4*)(SA + bIdx*HW + pbase) = sacc;
        f32x4 yv;
#pragma unroll
        for (int P = 0; P < 4; ++P) yv[P] = yacc[P][3];
        f32x4 xv = *(const f32x4*)(xb + 3*HW + pbase);
        *(f32x4*)(ob + 3*HW + pbase) = xv + yv*mk;
    } else {
#pragma unroll
        for (int i = 0; i < 4; ++i) {
            int ch = 4*q + i;
            f32x4 yv;
#pragma unroll
            for (int P = 0; P < 4; ++P) yv[P] = yacc[P][i];
            f32x4 xv = *(const f32x4*)(xb + ch*HW + pbase);
            *(f32x4*)(ob + ch*HW + pbase) = xv + yv*mk;
        }
    }
}

// ---- Kernel BC: fused T = Smass/E and out[0..2] *= 3x3sum(T), 8x64 tiles ---
__global__ __launch_bounds__(256) void nca_bc(
    const float* __restrict__ x,
    const float* __restrict__ SA,
    float* __restrict__ out)
{
    __shared__ float sa[12][69];
    __shared__ float tt[10][67];
    int tid = threadIdx.x;
    int bb = blockIdx.x >> 9;                 // 512 tiles per batch
    int t2 = blockIdx.x & 511;
    int h0 = (t2 >> 3) << 3;                  // 64 h-tiles of 8 rows
    int w0 = (t2 & 7) << 6;                   // 8 w-tiles of 64 cols
    const float* sab = SA + bb*HW;

    for (int e = tid; e < 816; e += 256) {    // 12 x 68 SA halo
        int rr = e / 68, cc = e - rr*68;
        int gh = (h0 + rr - 2) & WMASK, gw = (w0 + cc - 2) & WMASK;
        sa[rr][cc] = sab[(gh<<9) | gw];
    }
    __syncthreads();

    const float* xb = x + bb*16*HW;
    for (int e = tid; e < 660; e += 256) {    // 10 x 66 T
        int rr = e / 66, cc = e - rr*66;
        float E = sa[rr  ][cc] + sa[rr  ][cc+1] + sa[rr  ][cc+2]
                + sa[rr+1][cc] + sa[rr+1][cc+1] + sa[rr+1][cc+2]
                + sa[rr+2][cc] + sa[rr+2][cc+1] + sa[rr+2][cc+2];
        int gh = (h0 + rr - 1) & WMASK, gw = (w0 + cc - 1) & WMASK;
        int g = (gh<<9) | gw;
        float Sm = xb[g] + xb[HW + g] + xb[2*HW + g];
        tt[rr][cc] = Sm / E;
    }
    __syncthreads();

    for (int e = tid; e < 512; e += 256) {    // 8 x 64 out
        int rr = e >> 6, cc = e & 63;
        float R = tt[rr  ][cc] + tt[rr  ][cc+1] + tt[rr  ][cc+2]
                + tt[rr+1][cc] + tt[rr+1][cc+1] + tt[rr+1][cc+2]
                + tt[rr+2][cc] + tt[rr+2][cc+1] + tt[rr+2][cc+2];
        int p = ((h0 + rr) << 9) | (w0 + cc);
        float* ob = out + bb*16*HW + p;
        ob[0]    *= R;
        ob[HW]   *= R;
        ob[2*HW] *= R;
    }
}

extern "C" void kernel_launch(void* const* d_in, const int* in_sizes, int n_in,
                              void* d_out, int out_size, void* d_ws, size_t ws_size,
                              hipStream_t stream) {
    const float* x     = (const float*)d_in[0];
    const float* rmask = (const float*)d_in[1];
    const float* w1w   = (const float*)d_in[2];
    const float* w1b   = (const float*)d_in[3];
    const float* w2w   = (const float*)d_in[4];
    float* out = (float*)d_out;

    float* SA = (float*)d_ws;                                        // 4 MiB
    unsigned int* wbuf = (unsigned int*)((char*)d_ws + 4*HW*sizeof(float));

    hipLaunchKernelGGL(nca_prep,     dim3(1),    dim3(256), 0, stream, w1w, w1b, w2w, wbuf);
    hipLaunchKernelGGL(nca_mlp_mfma, dim3(4096), dim3(256), 0, stream, x, rmask, wbuf, out, SA);
    hipLaunchKernelGGL(nca_bc,       dim3(2048), dim3(256), 0, stream, x, SA, out);
}

// Round 5
// 184.124 us; speedup vs baseline: 2.3594x; 1.0163x over previous
//
#include <hip/hip_runtime.h>

#define HW (512*512)
#define WMASK 511

typedef short bf16x8 __attribute__((ext_vector_type(8)));
typedef float f32x4 __attribute__((ext_vector_type(4)));
typedef unsigned int u32x4 __attribute__((ext_vector_type(4)));

__device__ __forceinline__ unsigned short f2bf(float f) {
    union { float f; unsigned int u; } v; v.f = f;
    unsigned int r = (v.u + 0x7FFFu + ((v.u >> 16) & 1u)) >> 16;   // RNE
    return (unsigned short)r;
}
// pack 2 f32 -> 2 bf16 RNE in ONE instruction (lo -> low16, hi -> high16)
__device__ __forceinline__ unsigned int CVT(float lo, float hi) {
    unsigned int r;
    asm("v_cvt_pk_bf16_f32 %0, %1, %2" : "=v"(r) : "v"(lo), "v"(hi));
    return r;
}
// percep K-permutation: c_new = s8*8 + b*4 + f -> ch = 2*s8+b, feature f
__device__ __forceinline__ int corig(int c) {
    int s8 = c >> 3, b = (c >> 2) & 1, f = c & 3;
    int ch = 2*s8 + b;
    return (f == 0) ? ch : (16 + ch*3 + (f - 1));
}

// ---- prep: stage weights into MFMA-fragment layout in ws (1 block, once) ---
__global__ __launch_bounds__(256) void nca_prep(
    const float* __restrict__ w1w, const float* __restrict__ w1b,
    const float* __restrict__ w2w, unsigned int* __restrict__ wbuf)
{
    int tid = threadIdx.x;
    for (int u = tid; u < 4096; u += 256) {          // w1 fragments
        int m2 = u >> 8, ln = (u >> 2) & 63, d = u & 3;
        int m = m2 >> 1, ks = m2 & 1;
        int qq = ln >> 4, row = ln & 15;
        int c0 = ks*32 + qq*8 + 2*d;
        int hr = m*16 + row;
        unsigned int lo = f2bf(w1w[hr*64 + corig(c0)]);
        unsigned int hi = f2bf(w1w[hr*64 + corig(c0+1)]);
        wbuf[u] = lo | (hi << 16);
    }
    for (int u = tid; u < 1024; u += 256) {          // w2 fragments
        int s = u >> 8, ln = (u >> 2) & 63, d = u & 3;
        int qq = ln >> 4, ych = ln & 15;
        int k0 = s*32 + qq*8 + 2*d;
        unsigned int lo = f2bf(w2w[ych*128 + k0]);
        unsigned int hi = f2bf(w2w[ych*128 + k0 + 1]);
        wbuf[4096 + u] = lo | (hi << 16);
    }
    if (tid < 128) {                                 // bias (fp32 bits)
        union { float f; unsigned int u; } v; v.f = w1b[tid];
        wbuf[5120 + tid] = v.u;
    }
}

// ---- Kernel A: percep -> bf16 MFMA MLP -> normals + Aff + SA + Smass -------
__global__ __launch_bounds__(256) void nca_mlp_mfma(
    const float* __restrict__ x,
    const float* __restrict__ rmask,
    const unsigned int* __restrict__ wbuf,
    float* __restrict__ out,
    float* __restrict__ SA,
    float* __restrict__ SM)
{
    __shared__ __align__(16) unsigned int wsh[5248];     // 21 KB: w1|w2|bias
    __shared__ __align__(16) unsigned int hx[4][4][256]; // 16 KB: per-wave,per-P h scratch
    int tid  = threadIdx.x;
    int lane = tid & 63;
    int wv   = tid >> 6;
    int q    = lane >> 4;
    int r    = lane & 15;

    // coalesced LDS fill of pre-staged weights
    {
        const u32x4* src = (const u32x4*)wbuf;
        u32x4* dst = (u32x4*)wsh;
#pragma unroll
        for (int u = 0; u < 6; ++u) {
            int idx = tid + u*256;
            if (idx < 1312) dst[idx] = src[idx];
        }
    }

    // geometry: block = 4 rows x 64 cols; wave wv owns one row; lane r owns
    // pixels (cols) c4..c4+3  (fragment P column r <-> pixel w0+4r+P)
    int bIdx = blockIdx.x >> 10;
    int rem  = blockIdx.x & 1023;
    int hrow = ((rem >> 3) << 2) + wv;
    int w0   = (rem & 7) << 6;
    int c4   = w0 + (r << 2);
    int cl   = (c4 - 1) & WMASK;
    int cr   = (c4 + 4) & WMASK;
    int rm = ((hrow-1)&WMASK)<<9, rc = hrow<<9, rp = ((hrow+1)&WMASK)<<9;
    const float* xb = x + bIdx*16*HW;

    // percep fragments: direct 9-point stencil (round-4-exact), CVT pack
    union PFU { unsigned int u[4]; bf16x8 v; } pf[4][2];
    f32x4 c_sav0, c_sav1;        // ks=0 centers (q==0 lanes: ch0, ch1)
#pragma unroll
    for (int ks = 0; ks < 2; ++ks) {
#pragma unroll
        for (int b2 = 0; b2 < 2; ++b2) {
            const float* pl = xb + (8*ks + 2*q + b2)*HW;
            f32x4 m0 = *(const f32x4*)(pl + rm + c4);
            f32x4 m1 = *(const f32x4*)(pl + rc + c4);
            f32x4 m2 = *(const f32x4*)(pl + rp + c4);
            if (ks == 0) { if (b2 == 0) c_sav0 = m1; else c_sav1 = m1; }
            float col[6][3];
            col[0][0] = pl[rm+cl]; col[0][1] = pl[rc+cl]; col[0][2] = pl[rp+cl];
#pragma unroll
            for (int j = 0; j < 4; ++j) {
                col[j+1][0] = m0[j]; col[j+1][1] = m1[j]; col[j+1][2] = m2[j];
            }
            col[5][0] = pl[rm+cr]; col[5][1] = pl[rc+cr]; col[5][2] = pl[rp+cr];
#pragma unroll
            for (int p = 0; p < 4; ++p) {
                float a00 = col[p][0],   a01 = col[p+1][0], a02 = col[p+2][0];
                float a10 = col[p][1],   a11 = col[p+1][1], a12 = col[p+2][1];
                float a20 = col[p][2],   a21 = col[p+1][2], a22 = col[p+2][2];
                float sx = (a02 - a00) + 2.f*(a12 - a10) + (a22 - a20);
                float sy = (a20 - a00) + 2.f*(a21 - a01) + (a22 - a02);
                float lp = a00 + 2.f*a01 + a02
                         + 2.f*a10 - 12.f*a11 + 2.f*a12
                         + a20 + 2.f*a21 + a22;
                pf[p][ks].u[2*b2]   = CVT(a11, sx);
                pf[p][ks].u[2*b2+1] = CVT(sy, lp);
            }
        }
    }

    __syncthreads();

    const unsigned short* w1s = (const unsigned short*)wsh;
    const unsigned short* w2s = (const unsigned short*)(wsh + 4096);
    const float* w1bs = (const float*)(wsh + 5120);

    // h-transpose scratch indices (u32 units), swizzle col' = r ^ k8
    unsigned int* hbase = &hx[wv][0][0];
    int k8a = (q >> 1);              // t=0 rows 4q..4q+3
    int k8b = 2 + (q >> 1);          // t=1 rows 16+4q..+3
    int wi0 = k8a*64 + ((r ^ k8a) << 2) + ((q & 1) << 1);
    int wi1 = k8b*64 + ((r ^ k8b) << 2) + ((q & 1) << 1);
    int ri  = q*64 + ((r ^ q) << 2);

    f32x4 yacc[4];
#pragma unroll
    for (int P = 0; P < 4; ++P) { yacc[P][0]=0.f; yacc[P][1]=0.f; yacc[P][2]=0.f; yacc[P][3]=0.f; }

#pragma unroll
    for (int s = 0; s < 4; ++s) {
        f32x4 Hc[2][4];
#pragma unroll
        for (int t = 0; t < 2; ++t)
#pragma unroll
            for (int P = 0; P < 4; ++P) { Hc[t][P][0]=0.f; Hc[t][P][1]=0.f; Hc[t][P][2]=0.f; Hc[t][P][3]=0.f; }

#pragma unroll
        for (int t = 0; t < 2; ++t) {
#pragma unroll
            for (int ks = 0; ks < 2; ++ks) {
                bf16x8 af = *(const bf16x8*)&w1s[(((2*s+t)*2 + ks)*64 + lane)*8];
#pragma unroll
                for (int P = 0; P < 4; ++P)
                    Hc[t][P] = __builtin_amdgcn_mfma_f32_16x16x32_bf16(af, pf[P][ks].v, Hc[t][P], 0, 0, 0);
            }
        }

        bf16x8 wf = *(const bf16x8*)&w2s[(s*64 + lane)*8];
        float bi0[2][4];
#pragma unroll
        for (int t = 0; t < 2; ++t) {
            const float* bp = &w1bs[(2*s+t)*16 + (q<<2)];
#pragma unroll
            for (int i = 0; i < 4; ++i) bi0[t][i] = bp[i];
        }

        // bias+relu+pack, write h into per-P scratch (rows t*16+4q..+3, col r)
#pragma unroll
        for (int P = 0; P < 4; ++P) {
            unsigned int pk00, pk01, pk10, pk11;
            {
                f32x4 hv = Hc[0][P];
                float h0 = fmaxf(hv[0] + bi0[0][0], 0.f);
                float h1 = fmaxf(hv[1] + bi0[0][1], 0.f);
                float h2 = fmaxf(hv[2] + bi0[0][2], 0.f);
                float h3 = fmaxf(hv[3] + bi0[0][3], 0.f);
                pk00 = CVT(h0, h1); pk01 = CVT(h2, h3);
            }
            {
                f32x4 hv = Hc[1][P];
                float h0 = fmaxf(hv[0] + bi0[1][0], 0.f);
                float h1 = fmaxf(hv[1] + bi0[1][1], 0.f);
                float h2 = fmaxf(hv[2] + bi0[1][2], 0.f);
                float h3 = fmaxf(hv[3] + bi0[1][3], 0.f);
                pk10 = CVT(h0, h1); pk11 = CVT(h2, h3);
            }
            unsigned int* hb = hbase + P*256;
            *reinterpret_cast<unsigned long long*>(&hb[wi0]) =
                (unsigned long long)pk00 | ((unsigned long long)pk01 << 32);
            *reinterpret_cast<unsigned long long*>(&hb[wi1]) =
                (unsigned long long)pk10 | ((unsigned long long)pk11 << 32);
        }
        // read back as L2 B-fragments (k = 8q..8q+7, col r) and accumulate
#pragma unroll
        for (int P = 0; P < 4; ++P) {
            bf16x8 bv = *reinterpret_cast<const bf16x8*>(&hbase[P*256 + ri]);
            yacc[P] = __builtin_amdgcn_mfma_f32_16x16x32_bf16(wf, bv, yacc[P], 0, 0, 0);
        }
    }

    // epilogue: yacc[P][i] = y[ch=4q+i][pixel c4+P]; all IO as float4
    int pbase = rc + c4;
    f32x4 mk = *(const f32x4*)(rmask + bIdx*HW + pbase);
#pragma unroll
    for (int i = 0; i < 4; ++i) mk[i] = floorf(mk[i] + 0.5f);
    float* ob = out + bIdx*16*HW;

    if (q == 0) {
        f32x4 sacc;
#pragma unroll
        for (int i = 0; i < 3; ++i) {
            f32x4 A;
#pragma unroll
            for (int P = 0; P < 4; ++P) A[P] = expf(0.1f * yacc[P][i]);
            *(f32x4*)(ob + i*HW + pbase) = A;
            if (i == 0) sacc = A; else sacc += A;
        }
        *(f32x4*)(SA + bIdx*HW + pbase) = sacc;
        // Smass = x0+x1+x2 at center
        f32x4 x2v = *(const f32x4*)(xb + 2*HW + pbase);
        *(f32x4*)(SM + bIdx*HW + pbase) = c_sav0 + c_sav1 + x2v;
        f32x4 yv;
#pragma unroll
        for (int P = 0; P < 4; ++P) yv[P] = yacc[P][3];
        f32x4 xv = *(const f32x4*)(xb + 3*HW + pbase);
        *(f32x4*)(ob + 3*HW + pbase) = xv + yv*mk;
    } else {
#pragma unroll
        for (int i = 0; i < 4; ++i) {
            int ch = 4*q + i;
            f32x4 yv;
#pragma unroll
            for (int P = 0; P < 4; ++P) yv[P] = yacc[P][i];
            f32x4 xv = *(const f32x4*)(xb + ch*HW + pbase);
            *(f32x4*)(ob + ch*HW + pbase) = xv + yv*mk;
        }
    }
}

// ---- Kernel BC: fused T = Smass/E and out[0..2] *= 3x3sum(T), 8x64 tiles ---
__global__ __launch_bounds__(256) void nca_bc(
    const float* __restrict__ SA,
    const float* __restrict__ SM,
    float* __restrict__ out)
{
    __shared__ float sa[12][69];
    __shared__ float tt[10][67];
    int tid = threadIdx.x;
    int bb = blockIdx.x >> 9;                 // 512 tiles per batch
    int t2 = blockIdx.x & 511;
    int h0 = (t2 >> 3) << 3;                  // 64 h-tiles of 8 rows
    int w0 = (t2 & 7) << 6;                   // 8 w-tiles of 64 cols
    const float* sab = SA + bb*HW;
    const float* smb = SM + bb*HW;

    for (int e = tid; e < 816; e += 256) {    // 12 x 68 SA halo
        int rr = e / 68, cc = e - rr*68;
        int gh = (h0 + rr - 2) & WMASK, gw = (w0 + cc - 2) & WMASK;
        sa[rr][cc] = sab[(gh<<9) | gw];
    }
    __syncthreads();

    for (int e = tid; e < 660; e += 256) {    // 10 x 66 T
        int rr = e / 66, cc = e - rr*66;
        float E = sa[rr  ][cc] + sa[rr  ][cc+1] + sa[rr  ][cc+2]
                + sa[rr+1][cc] + sa[rr+1][cc+1] + sa[rr+1][cc+2]
                + sa[rr+2][cc] + sa[rr+2][cc+1] + sa[rr+2][cc+2];
        int gh = (h0 + rr - 1) & WMASK, gw = (w0 + cc - 1) & WMASK;
        int g = (gh<<9) | gw;
        tt[rr][cc] = smb[g] / E;
    }
    __syncthreads();

    for (int e = tid; e < 512; e += 256) {    // 8 x 64 out
        int rr = e >> 6, cc = e & 63;
        float R = tt[rr  ][cc] + tt[rr  ][cc+1] + tt[rr  ][cc+2]
                + tt[rr+1][cc] + tt[rr+1][cc+1] + tt[rr+1][cc+2]
                + tt[rr+2][cc] + tt[rr+2][cc+1] + tt[rr+2][cc+2];
        int p = ((h0 + rr) << 9) | (w0 + cc);
        float* ob = out + bb*16*HW + p;
        ob[0]    *= R;
        ob[HW]   *= R;
        ob[2*HW] *= R;
    }
}

extern "C" void kernel_launch(void* const* d_in, const int* in_sizes, int n_in,
                              void* d_out, int out_size, void* d_ws, size_t ws_size,
                              hipStream_t stream) {
    const float* x     = (const float*)d_in[0];
    const float* rmask = (const float*)d_in[1];
    const float* w1w   = (const float*)d_in[2];
    const float* w1b   = (const float*)d_in[3];
    const float* w2w   = (const float*)d_in[4];
    float* out = (float*)d_out;

    float* SA = (float*)d_ws;                                        // 4 MiB
    float* SM = SA + 4*HW;                                           // 4 MiB
    unsigned int* wbuf = (unsigned int*)((char*)d_ws + 8*HW*sizeof(float));

    hipLaunchKernelGGL(nca_prep,     dim3(1),    dim3(256), 0, stream, w1w, w1b, w2w, wbuf);
    hipLaunchKernelGGL(nca_mlp_mfma, dim3(4096), dim3(256), 0, stream, x, rmask, wbuf, out, SA, SM);
    hipLaunchKernelGGL(nca_bc,       dim3(2048), dim3(256), 0, stream, SA, SM, out);
}

// Round 6
// 171.279 us; speedup vs baseline: 2.5364x; 1.0750x over previous
//
#include <hip/hip_runtime.h>

#define HW (512*512)
#define WMASK 511

typedef short bf16x8 __attribute__((ext_vector_type(8)));
typedef float f32x4 __attribute__((ext_vector_type(4)));
typedef unsigned int u32x4 __attribute__((ext_vector_type(4)));

__device__ __forceinline__ unsigned short f2bf(float f) {
    union { float f; unsigned int u; } v; v.f = f;
    unsigned int r = (v.u + 0x7FFFu + ((v.u >> 16) & 1u)) >> 16;   // RNE
    return (unsigned short)r;
}
// pack 2 f32 -> 2 bf16 RNE in ONE instruction (lo -> low16, hi -> high16)
__device__ __forceinline__ unsigned int CVT(float lo, float hi) {
    unsigned int r;
    asm("v_cvt_pk_bf16_f32 %0, %1, %2" : "=v"(r) : "v"(lo), "v"(hi));
    return r;
}
__device__ __forceinline__ float RCP(float x) {
    float r;
    asm("v_rcp_f32 %0, %1" : "=v"(r) : "v"(x));
    return r;
}
// percep K-permutation: c_new = s8*8 + b*4 + f -> ch = 2*s8+b, feature f
__device__ __forceinline__ int corig(int c) {
    int s8 = c >> 3, b = (c >> 2) & 1, f = c & 3;
    int ch = 2*s8 + b;
    return (f == 0) ? ch : (16 + ch*3 + (f - 1));
}

// ---- prep: stage weights into MFMA-fragment layout in ws (21 blocks) -------
__global__ __launch_bounds__(256) void nca_prep(
    const float* __restrict__ w1w, const float* __restrict__ w1b,
    const float* __restrict__ w2w, unsigned int* __restrict__ wbuf)
{
    int u = blockIdx.x * 256 + threadIdx.x;
    if (u < 4096) {                                  // w1 fragments
        int m2 = u >> 8, ln = (u >> 2) & 63, d = u & 3;
        int m = m2 >> 1, ks = m2 & 1;
        int qq = ln >> 4, row = ln & 15;
        int c0 = ks*32 + qq*8 + 2*d;
        int hr = m*16 + row;
        unsigned int lo = f2bf(w1w[hr*64 + corig(c0)]);
        unsigned int hi = f2bf(w1w[hr*64 + corig(c0+1)]);
        wbuf[u] = lo | (hi << 16);
    } else if (u < 5120) {                           // w2 fragments
        int v = u - 4096;
        int s = v >> 8, ln = (v >> 2) & 63, d = v & 3;
        int qq = ln >> 4, ych = ln & 15;
        int k0 = s*32 + qq*8 + 2*d;
        unsigned int lo = f2bf(w2w[ych*128 + k0]);
        unsigned int hi = f2bf(w2w[ych*128 + k0 + 1]);
        wbuf[u] = lo | (hi << 16);
    } else if (u < 5248) {                           // bias (fp32 bits)
        union { float f; unsigned int u; } v; v.f = w1b[u - 5120];
        wbuf[u] = v.u;
    }
}

// ---- Kernel A: percep -> bf16 MFMA MLP -> normals + Aff + SA + Smass -------
__global__ __launch_bounds__(256) void nca_mlp_mfma(
    const float* __restrict__ x,
    const float* __restrict__ rmask,
    const unsigned int* __restrict__ wbuf,
    float* __restrict__ out,
    float* __restrict__ SA,
    float* __restrict__ SM)
{
    __shared__ __align__(16) unsigned int wsh[5248];   // 21 KB: w1|w2|bias
    __shared__ __align__(16) unsigned int hx[4][256];  // 4 KB: per-wave h scratch (reused per P)
    int tid  = threadIdx.x;
    int lane = tid & 63;
    int wv   = tid >> 6;
    int q    = lane >> 4;
    int r    = lane & 15;

    // coalesced LDS fill of pre-staged weights
    {
        const u32x4* src = (const u32x4*)wbuf;
        u32x4* dst = (u32x4*)wsh;
#pragma unroll
        for (int u = 0; u < 6; ++u) {
            int idx = tid + u*256;
            if (idx < 1312) dst[idx] = src[idx];
        }
    }

    // geometry: block = 4 rows x 64 cols; wave wv owns one row; lane r owns
    // pixels (cols) c4..c4+3  (fragment P column r <-> pixel w0+4r+P)
    int bIdx = blockIdx.x >> 10;
    int rem  = blockIdx.x & 1023;
    int hrow = ((rem >> 3) << 2) + wv;
    int w0   = (rem & 7) << 6;
    int c4   = w0 + (r << 2);
    int cl   = (c4 - 1) & WMASK;
    int cr   = (c4 + 4) & WMASK;
    int rm = ((hrow-1)&WMASK)<<9, rc = hrow<<9, rp = ((hrow+1)&WMASK)<<9;
    const float* xb = x + bIdx*16*HW;

    // percep fragments: direct 9-point stencil, CVT pack
    union PFU { unsigned int u[4]; bf16x8 v; } pf[4][2];
    f32x4 c_sav0, c_sav1;        // ks=0 centers (q==0 lanes: ch0, ch1)
#pragma unroll
    for (int ks = 0; ks < 2; ++ks) {
#pragma unroll
        for (int b2 = 0; b2 < 2; ++b2) {
            const float* pl = xb + (8*ks + 2*q + b2)*HW;
            f32x4 m0 = *(const f32x4*)(pl + rm + c4);
            f32x4 m1 = *(const f32x4*)(pl + rc + c4);
            f32x4 m2 = *(const f32x4*)(pl + rp + c4);
            if (ks == 0) { if (b2 == 0) c_sav0 = m1; else c_sav1 = m1; }
            float col[6][3];
            col[0][0] = pl[rm+cl]; col[0][1] = pl[rc+cl]; col[0][2] = pl[rp+cl];
#pragma unroll
            for (int j = 0; j < 4; ++j) {
                col[j+1][0] = m0[j]; col[j+1][1] = m1[j]; col[j+1][2] = m2[j];
            }
            col[5][0] = pl[rm+cr]; col[5][1] = pl[rc+cr]; col[5][2] = pl[rp+cr];
#pragma unroll
            for (int p = 0; p < 4; ++p) {
                float a00 = col[p][0],   a01 = col[p+1][0], a02 = col[p+2][0];
                float a10 = col[p][1],   a11 = col[p+1][1], a12 = col[p+2][1];
                float a20 = col[p][2],   a21 = col[p+1][2], a22 = col[p+2][2];
                float sx = (a02 - a00) + 2.f*(a12 - a10) + (a22 - a20);
                float sy = (a20 - a00) + 2.f*(a21 - a01) + (a22 - a02);
                float lp = a00 + 2.f*a01 + a02
                         + 2.f*a10 - 12.f*a11 + 2.f*a12
                         + a20 + 2.f*a21 + a22;
                pf[p][ks].u[2*b2]   = CVT(a11, sx);
                pf[p][ks].u[2*b2+1] = CVT(sy, lp);
            }
        }
    }

    __syncthreads();

    const unsigned short* w1s = (const unsigned short*)wsh;
    const unsigned short* w2s = (const unsigned short*)(wsh + 4096);
    const float* w1bs = (const float*)(wsh + 5120);

    // h-transpose scratch indices (u32 units), swizzle col' = r ^ k8
    unsigned int* hbase = &hx[wv][0];
    int k8a = (q >> 1);              // t=0 rows 4q..4q+3
    int k8b = 2 + (q >> 1);          // t=1 rows 16+4q..+3
    int wi0 = k8a*64 + ((r ^ k8a) << 2) + ((q & 1) << 1);
    int wi1 = k8b*64 + ((r ^ k8b) << 2) + ((q & 1) << 1);
    int ri  = q*64 + ((r ^ q) << 2);

    f32x4 yacc[4];
#pragma unroll
    for (int P = 0; P < 4; ++P) { yacc[P][0]=0.f; yacc[P][1]=0.f; yacc[P][2]=0.f; yacc[P][3]=0.f; }

#pragma unroll
    for (int s = 0; s < 4; ++s) {
        f32x4 Hc[2][4];
#pragma unroll
        for (int t = 0; t < 2; ++t)
#pragma unroll
            for (int P = 0; P < 4; ++P) { Hc[t][P][0]=0.f; Hc[t][P][1]=0.f; Hc[t][P][2]=0.f; Hc[t][P][3]=0.f; }

#pragma unroll
        for (int t = 0; t < 2; ++t) {
#pragma unroll
            for (int ks = 0; ks < 2; ++ks) {
                bf16x8 af = *(const bf16x8*)&w1s[(((2*s+t)*2 + ks)*64 + lane)*8];
#pragma unroll
                for (int P = 0; P < 4; ++P)
                    Hc[t][P] = __builtin_amdgcn_mfma_f32_16x16x32_bf16(af, pf[P][ks].v, Hc[t][P], 0, 0, 0);
            }
        }

        bf16x8 wf = *(const bf16x8*)&w2s[(s*64 + lane)*8];
        f32x4 bi[2];
#pragma unroll
        for (int t = 0; t < 2; ++t)
            bi[t] = *(const f32x4*)&w1bs[(2*s+t)*16 + (q<<2)];

        // per P: bias+relu+pack -> LDS write -> read back as B-frag -> MFMA.
        // Same-wave DS ops execute in issue order; region reused across P.
#pragma unroll
        for (int P = 0; P < 4; ++P) {
            unsigned int pk00, pk01, pk10, pk11;
            {
                f32x4 hv = Hc[0][P];
                float h0 = fmaxf(hv[0] + bi[0][0], 0.f);
                float h1 = fmaxf(hv[1] + bi[0][1], 0.f);
                float h2 = fmaxf(hv[2] + bi[0][2], 0.f);
                float h3 = fmaxf(hv[3] + bi[0][3], 0.f);
                pk00 = CVT(h0, h1); pk01 = CVT(h2, h3);
            }
            {
                f32x4 hv = Hc[1][P];
                float h0 = fmaxf(hv[0] + bi[1][0], 0.f);
                float h1 = fmaxf(hv[1] + bi[1][1], 0.f);
                float h2 = fmaxf(hv[2] + bi[1][2], 0.f);
                float h3 = fmaxf(hv[3] + bi[1][3], 0.f);
                pk10 = CVT(h0, h1); pk11 = CVT(h2, h3);
            }
            *reinterpret_cast<unsigned long long*>(&hbase[wi0]) =
                (unsigned long long)pk00 | ((unsigned long long)pk01 << 32);
            *reinterpret_cast<unsigned long long*>(&hbase[wi1]) =
                (unsigned long long)pk10 | ((unsigned long long)pk11 << 32);
            bf16x8 bv = *reinterpret_cast<const bf16x8*>(&hbase[ri]);
            yacc[P] = __builtin_amdgcn_mfma_f32_16x16x32_bf16(wf, bv, yacc[P], 0, 0, 0);
        }
    }

    // epilogue: yacc[P][i] = y[ch=4q+i][pixel c4+P]; all IO as float4
    int pbase = rc + c4;
    f32x4 mk = *(const f32x4*)(rmask + bIdx*HW + pbase);
#pragma unroll
    for (int i = 0; i < 4; ++i) mk[i] = floorf(mk[i] + 0.5f);
    float* ob = out + bIdx*16*HW;

    if (q == 0) {
        f32x4 sacc;
#pragma unroll
        for (int i = 0; i < 3; ++i) {
            f32x4 A;
#pragma unroll
            for (int P = 0; P < 4; ++P) A[P] = expf(0.1f * yacc[P][i]);
            *(f32x4*)(ob + i*HW + pbase) = A;
            if (i == 0) sacc = A; else sacc += A;
        }
        *(f32x4*)(SA + bIdx*HW + pbase) = sacc;
        // Smass = x0+x1+x2 at center
        f32x4 x2v = *(const f32x4*)(xb + 2*HW + pbase);
        *(f32x4*)(SM + bIdx*HW + pbase) = c_sav0 + c_sav1 + x2v;
        f32x4 yv;
#pragma unroll
        for (int P = 0; P < 4; ++P) yv[P] = yacc[P][3];
        f32x4 xv = *(const f32x4*)(xb + 3*HW + pbase);
        *(f32x4*)(ob + 3*HW + pbase) = xv + yv*mk;
    } else {
#pragma unroll
        for (int i = 0; i < 4; ++i) {
            int ch = 4*q + i;
            f32x4 yv;
#pragma unroll
            for (int P = 0; P < 4; ++P) yv[P] = yacc[P][i];
            f32x4 xv = *(const f32x4*)(xb + ch*HW + pbase);
            *(f32x4*)(ob + ch*HW + pbase) = xv + yv*mk;
        }
    }
}

// ---- Kernel BC: fused T = Smass/E and out[0..2] *= 3x3sum(T), 8x64 tiles ---
__global__ __launch_bounds__(256) void nca_bc(
    const float* __restrict__ SA,
    const float* __restrict__ SM,
    float* __restrict__ out)
{
    __shared__ float sa[12][69];
    __shared__ float tt[10][67];
    int tid = threadIdx.x;
    int bb = blockIdx.x >> 9;                 // 512 tiles per batch
    int t2 = blockIdx.x & 511;
    int h0 = (t2 >> 3) << 3;                  // 64 h-tiles of 8 rows
    int w0 = (t2 & 7) << 6;                   // 8 w-tiles of 64 cols
    const float* sab = SA + bb*HW;
    const float* smb = SM + bb*HW;

    for (int e = tid; e < 816; e += 256) {    // 12 x 68 SA halo
        int rr = e / 68, cc = e - rr*68;
        int gh = (h0 + rr - 2) & WMASK, gw = (w0 + cc - 2) & WMASK;
        sa[rr][cc] = sab[(gh<<9) | gw];
    }
    __syncthreads();

    for (int e = tid; e < 660; e += 256) {    // 10 x 66 T
        int rr = e / 66, cc = e - rr*66;
        float E = sa[rr  ][cc] + sa[rr  ][cc+1] + sa[rr  ][cc+2]
                + sa[rr+1][cc] + sa[rr+1][cc+1] + sa[rr+1][cc+2]
                + sa[rr+2][cc] + sa[rr+2][cc+1] + sa[rr+2][cc+2];
        int gh = (h0 + rr - 1) & WMASK, gw = (w0 + cc - 1) & WMASK;
        int g = (gh<<9) | gw;
        tt[rr][cc] = smb[g] * RCP(E);
    }
    __syncthreads();

    for (int e = tid; e < 512; e += 256) {    // 8 x 64 out
        int rr = e >> 6, cc = e & 63;
        float R = tt[rr  ][cc] + tt[rr  ][cc+1] + tt[rr  ][cc+2]
                + tt[rr+1][cc] + tt[rr+1][cc+1] + tt[rr+1][cc+2]
                + tt[rr+2][cc] + tt[rr+2][cc+1] + tt[rr+2][cc+2];
        int p = ((h0 + rr) << 9) | (w0 + cc);
        float* ob = out + bb*16*HW + p;
        ob[0]    *= R;
        ob[HW]   *= R;
        ob[2*HW] *= R;
    }
}

extern "C" void kernel_launch(void* const* d_in, const int* in_sizes, int n_in,
                              void* d_out, int out_size, void* d_ws, size_t ws_size,
                              hipStream_t stream) {
    const float* x     = (const float*)d_in[0];
    const float* rmask = (const float*)d_in[1];
    const float* w1w   = (const float*)d_in[2];
    const float* w1b   = (const float*)d_in[3];
    const float* w2w   = (const float*)d_in[4];
    float* out = (float*)d_out;

    float* SA = (float*)d_ws;                                        // 4 MiB
    float* SM = SA + 4*HW;                                           // 4 MiB
    unsigned int* wbuf = (unsigned int*)((char*)d_ws + 8*HW*sizeof(float));

    hipLaunchKernelGGL(nca_prep,     dim3(21),   dim3(256), 0, stream, w1w, w1b, w2w, wbuf);
    hipLaunchKernelGGL(nca_mlp_mfma, dim3(4096), dim3(256), 0, stream, x, rmask, wbuf, out, SA, SM);
    hipLaunchKernelGGL(nca_bc,       dim3(2048), dim3(256), 0, stream, SA, SM, out);
}